// Round 6
// baseline (206.121 us; speedup 1.0000x reference)
//
#include <hip/hip_runtime.h>
#include <math.h>

// Problem constants (from reference): N=100000, S=64, Q=50, P=3
#define N_Q 50
#define N_P 3
#define N_S 64
#define ROW 150        // Q*P floats per pauli word
#define BLK_ROWS 64    // rows per block (1 per lane) -> 6256 waves total
#define THREADS 256    // 4 waves; wave w handles s in [16w, 16w+16)
#define WAVES 4
#define SCHUNK 16

// ws layout (bytes):
//   [0      .. 12504)   partials double[1563]
//   [12544  .. +4)      done-counter int (zeroed by precompute each launch)
//   [12608  .. +38400)  HP   float[Q][S][3]  normalized heads, q-major
//   [51008  .. +256)    hrv  float[S]        smoothed head ratios
#define WS_CNT_OFF 12544
#define WS_HP_OFF 12608
#define WS_HRV_OFF 51008

__device__ __forceinline__ float softplus20(float x) {
    float z = x * 20.0f;
    return fmaxf(z, 0.0f) + log1pf(expf(-fabsf(z)));  // stable softplus
}

__global__ void precompute_kernel(const float* __restrict__ heads_param,
                                  const float* __restrict__ hr_param,
                                  float* __restrict__ HP,
                                  float* __restrict__ hrv,
                                  int* __restrict__ cnt) {
    const int tid = threadIdx.x;
    if (blockIdx.x == 0) {
        if (tid == 0) *cnt = 0;  // ws is re-poisoned every launch
        if (tid < N_S) {
            float sp = softplus20(hr_param[tid]);
            float tot = sp;
            #pragma unroll
            for (int off = 32; off; off >>= 1) tot += __shfl_xor(tot, off);
            float hr = sp / fmaxf(tot, 1e-12f);
            hrv[tid] = (hr + 0.001f / (float)N_S) / 1.001f;
        }
    }
    // EXACT reference semantics: h_p = sp_p / max(sum, EPS); when the clamp
    // fires the row does NOT sum to 1, so all three components are stored.
    int idx = blockIdx.x * blockDim.x + tid;
    if (idx < N_S * N_Q) {
        int q = idx / N_S;
        int s = idx - q * N_S;
        const float* hp = heads_param + ((size_t)s * N_Q + q) * N_P;
        float sp0 = softplus20(hp[0]);
        float sp1 = softplus20(hp[1]);
        float sp2 = softplus20(hp[2]);
        float denom = fmaxf(sp0 + sp1 + sp2, 1e-12f);
        float* o = HP + ((size_t)q * N_S + s) * 3;
        o[0] = sp0 / denom;
        o[1] = sp1 / denom;
        o[2] = sp2 / denom;
    }
}

// One q, 16 s-values (4 groups of 4), ONE row per lane. Hq is a wave-uniform
// LDS pointer -> conflict-free broadcast ds_read_b128 (the proven r0 path).
// Math order identical to the verified kernels (absmax stayed 0).
__device__ __forceinline__ void computeQ1(const float4* __restrict__ Hq,
                                          float a0, float a1, float a2,
                                          float (&p)[SCHUNK]) {
    #pragma unroll
    for (int g = 0; g < 4; ++g) {
        float4 b0 = Hq[3 * g], b1 = Hq[3 * g + 1], b2 = Hq[3 * g + 2];
        // layout per 4 s: [h00 h01 h02 h10][h11 h12 h20 h21][h22 h30 h31 h32]
        p[4*g+0] *= fmaf(b0.x, a0, fmaf(b0.y, a1, b0.z * a2));
        p[4*g+1] *= fmaf(b0.w, a0, fmaf(b1.x, a1, b1.y * a2));
        p[4*g+2] *= fmaf(b1.z, a0, fmaf(b1.w, a1, b2.x * a2));
        p[4*g+3] *= fmaf(b2.y, a0, fmaf(b2.z, a1, b2.w * a2));
    }
}

__global__ __launch_bounds__(THREADS) void main_kernel(
    const float* __restrict__ A, const float* __restrict__ coeff,
    const float* __restrict__ HP, const float* __restrict__ hrv,
    double* __restrict__ partials, int* __restrict__ cnt,
    float* __restrict__ out, int N) {
    __shared__ float hHs[N_Q * N_S * 3];     // 38400 B, q-major
    __shared__ float hrvl[N_S];
    __shared__ float covs[WAVES][BLK_ROWS];  // 1024 B
    __shared__ double redf[WAVES];
    __shared__ int isLast;

    const int tid = threadIdx.x;
    const int lane = tid & 63;
    const int wave = tid >> 6;
    const int nbase = blockIdx.x * BLK_ROWS;

    // --- stage H (+hrv) into LDS once per block, coalesced float4 ---
    for (int i = tid; i < (N_Q * N_S * 3) / 4; i += THREADS)
        ((float4*)hHs)[i] = ((const float4*)HP)[i];
    if (tid < N_S) hrvl[tid] = hrv[tid];
    __syncthreads();

    // lane owns row n0 = nbase + lane (same rows for all 4 waves -> R=4,
    // total scattered A wave-loads identical to the 83us round-0 kernel)
    int n0 = nbase + lane;  if (n0 >= N) n0 = N - 1;
    const float2* __restrict__ pA0 = (const float2*)A + (size_t)n0 * (ROW / 2);

    float prod[SCHUNK];
    #pragma unroll
    for (int i = 0; i < SCHUNK; ++i) prod[i] = 1.0f;

    // H base for this wave's s-chunk: q-row = 48 float4; wave offset 12*wave
    const float4* __restrict__ Hbase = (const float4*)hHs + 12 * wave;

    // window = 2 q = 6 floats/row; one-window A prefetch (6 floats live extra)
    float2 x0 = pA0[0], x1 = pA0[1], x2 = pA0[2];

    #pragma unroll 5
    for (int w = 0; w < N_Q / 2; ++w) {
        const int nb = (w < N_Q / 2 - 1) ? 3 * w + 3 : 0;  // clamped, always valid
        float2 nx0 = pA0[nb], nx1 = pA0[nb + 1], nx2 = pA0[nb + 2];
        const float4* Hq = Hbase + 96 * w;      // q = 2w -> row offset 2w*48
        computeQ1(Hq,      x0.x, x0.y, x1.x, prod);
        computeQ1(Hq + 48, x1.y, x2.x, x2.y, prod);
        x0 = nx0; x1 = nx1; x2 = nx2;
    }

    // ratio-weighted partial for this wave's s-chunk (16-long fmaf chain,
    // same association as all verified rounds)
    float acc = 0.0f;
    const int s0 = wave * SCHUNK;
    #pragma unroll
    for (int i = 0; i < SCHUNK; ++i) acc = fmaf(hrvl[s0 + i], prod[i], acc);
    covs[wave][lane] = acc;
    __syncthreads();

    // wave 0 finalizes all 64 rows; cov = ((c0+c1)+c2)+c3 sequential (exact)
    double td = 0.0;
    if (wave == 0) {
        float cov = covs[0][lane] + covs[1][lane] + covs[2][lane] + covs[3][lane];
        float term = 0.0f;
        int n = nbase + lane;
        if (n < N) { float c = coeff[n]; term = (c * c) / cov; }
        td = (double)term;
        #pragma unroll
        for (int off = 32; off; off >>= 1) td += __shfl_down(td, off);
    }

    if (tid == 0) {
        partials[blockIdx.x] = td;
        __threadfence();                 // release partial
        int v = atomicAdd(cnt, 1);
        isLast = (v == (int)gridDim.x - 1);
    }
    __syncthreads();

    if (isLast) {                        // last-finishing block reduces all
        __threadfence();                 // acquire
        double s = 0.0;
        for (int i = tid; i < (int)gridDim.x; i += THREADS) s += partials[i];
        #pragma unroll
        for (int off = 32; off; off >>= 1) s += __shfl_down(s, off);
        if (lane == 0) redf[wave] = s;
        __syncthreads();
        if (tid == 0) {
            double t = 0.0;
            #pragma unroll
            for (int wv = 0; wv < WAVES; ++wv) t += redf[wv];
            out[0] = (float)t;
        }
    }
}

extern "C" void kernel_launch(void* const* d_in, const int* in_sizes, int n_in,
                              void* d_out, int out_size, void* d_ws, size_t ws_size,
                              hipStream_t stream) {
    const float* A           = (const float*)d_in[0];  // [N, Q, P]
    const float* coeff       = (const float*)d_in[1];  // [N]
    const float* heads_param = (const float*)d_in[2];  // [S, Q, P]
    const float* hr_param    = (const float*)d_in[3];  // [S]
    const int N = in_sizes[1];
    const int nblocks = (N + BLK_ROWS - 1) / BLK_ROWS;  // 1563

    char* ws = (char*)d_ws;
    double* partials = (double*)ws;
    int*   cnt = (int*)(ws + WS_CNT_OFF);
    float* HP  = (float*)(ws + WS_HP_OFF);
    float* hrv = (float*)(ws + WS_HRV_OFF);
    float* out = (float*)d_out;

    const int pre_blocks = (N_S * N_Q + THREADS - 1) / THREADS;  // 13
    precompute_kernel<<<pre_blocks, THREADS, 0, stream>>>(heads_param, hr_param,
                                                          HP, hrv, cnt);
    main_kernel<<<nblocks, THREADS, 0, stream>>>(A, coeff, HP, hrv, partials,
                                                 cnt, out, N);
}

// Round 7
// 152.526 us; speedup vs baseline: 1.3514x; 1.3514x over previous
//
#include <hip/hip_runtime.h>
#include <math.h>

// Problem constants (from reference): N=100000, S=64, Q=50, P=3
#define N_Q 50
#define N_P 3
#define N_S 64
#define ROW 150        // Q*P floats per pauli word
#define BLK_ROWS 256   // rows per block (4 per lane)
#define THREADS 256    // 4 waves; wave w handles s in [16w, 16w+16)
#define WAVES 4
#define SCHUNK 16
#define RPL 4          // rows per lane: row r -> nbase + 64*r + lane

// ws layout (bytes):
//   [0     .. 3128)    partials double[391]
//   [3200  .. +4)      done-counter int (zeroed by precompute each launch)
//   [3264  .. +38400)  HP   float[Q][S][3]  normalized heads, q-major
//   [41664 .. +256)    hrv  float[S]        smoothed head ratios
#define WS_CNT_OFF 3200
#define WS_HP_OFF 3264
#define WS_HRV_OFF 41664

__device__ __forceinline__ float softplus20(float x) {
    float z = x * 20.0f;
    return fmaxf(z, 0.0f) + log1pf(expf(-fabsf(z)));  // stable softplus
}

__global__ void precompute_kernel(const float* __restrict__ heads_param,
                                  const float* __restrict__ hr_param,
                                  float* __restrict__ HP,
                                  float* __restrict__ hrv,
                                  int* __restrict__ cnt) {
    const int tid = threadIdx.x;
    if (blockIdx.x == 0) {
        if (tid == 0) *cnt = 0;  // ws is re-poisoned every launch
        if (tid < N_S) {
            float sp = softplus20(hr_param[tid]);
            float tot = sp;
            #pragma unroll
            for (int off = 32; off; off >>= 1) tot += __shfl_xor(tot, off);
            float hr = sp / fmaxf(tot, 1e-12f);
            hrv[tid] = (hr + 0.001f / (float)N_S) / 1.001f;
        }
    }
    // EXACT reference semantics: h_p = sp_p / max(sum, EPS); when the clamp
    // fires the row does NOT sum to 1, so all three components are stored.
    int idx = blockIdx.x * blockDim.x + tid;
    if (idx < N_S * N_Q) {
        int q = idx / N_S;
        int s = idx - q * N_S;
        const float* hp = heads_param + ((size_t)s * N_Q + q) * N_P;
        float sp0 = softplus20(hp[0]);
        float sp1 = softplus20(hp[1]);
        float sp2 = softplus20(hp[2]);
        float denom = fmaxf(sp0 + sp1 + sp2, 1e-12f);
        float* o = HP + ((size_t)q * N_S + s) * 3;
        o[0] = sp0 / denom;
        o[1] = sp1 / denom;
        o[2] = sp2 / denom;
    }
}

// One q, 16 s-values (4 groups of 4), applied to FOUR rows sharing the H
// reads (16 FMA-ops per float4 read -> ds_read latency hidden by compute).
// Hq is wave-uniform -> conflict-free LDS broadcast (proven r0 path).
// Per-(s,q,row) math order identical to all verified rounds.
__device__ __forceinline__ void computeQ4(const float4* __restrict__ Hq,
                                          const float (&a)[RPL][3],
                                          float (&p)[RPL][SCHUNK]) {
    #pragma unroll
    for (int g = 0; g < 4; ++g) {
        float4 b0 = Hq[3 * g], b1 = Hq[3 * g + 1], b2 = Hq[3 * g + 2];
        // layout per 4 s: [h00 h01 h02 h10][h11 h12 h20 h21][h22 h30 h31 h32]
        #pragma unroll
        for (int r = 0; r < RPL; ++r) {
            p[r][4*g+0] *= fmaf(b0.x, a[r][0], fmaf(b0.y, a[r][1], b0.z * a[r][2]));
            p[r][4*g+1] *= fmaf(b0.w, a[r][0], fmaf(b1.x, a[r][1], b1.y * a[r][2]));
            p[r][4*g+2] *= fmaf(b1.z, a[r][0], fmaf(b1.w, a[r][1], b2.x * a[r][2]));
            p[r][4*g+3] *= fmaf(b2.y, a[r][0], fmaf(b2.z, a[r][1], b2.w * a[r][2]));
        }
    }
}

__global__ __launch_bounds__(THREADS, 2) void main_kernel(
    const float* __restrict__ A, const float* __restrict__ coeff,
    const float* __restrict__ HP, const float* __restrict__ hrv,
    double* __restrict__ partials, int* __restrict__ cnt,
    float* __restrict__ out, int N) {
    __shared__ float hHs[N_Q * N_S * 3];     // 38400 B, q-major
    __shared__ float hrvl[N_S];
    __shared__ float covs[WAVES][BLK_ROWS];  // 4096 B
    __shared__ double redd[WAVES];
    __shared__ double redf[WAVES];
    __shared__ int isLast;

    const int tid = threadIdx.x;
    const int lane = tid & 63;
    const int wave = tid >> 6;
    const int nbase = blockIdx.x * BLK_ROWS;

    // --- stage H (+hrv) into LDS once per block, coalesced float4 ---
    for (int i = tid; i < (N_Q * N_S * 3) / 4; i += THREADS)
        ((float4*)hHs)[i] = ((const float4*)HP)[i];
    if (tid < N_S) hrvl[tid] = hrv[tid];
    __syncthreads();

    // lane owns rows nbase + 64r + lane, r=0..3 (same rows for all 4 waves:
    // total scattered A wave-loads identical to the 83us round-0 kernel)
    const float2* __restrict__ pR[RPL];
    #pragma unroll
    for (int r = 0; r < RPL; ++r) {
        int n = nbase + 64 * r + lane;  if (n >= N) n = N - 1;
        pR[r] = (const float2*)A + (size_t)n * (ROW / 2);
    }

    float prod[RPL][SCHUNK];
    #pragma unroll
    for (int r = 0; r < RPL; ++r)
        #pragma unroll
        for (int i = 0; i < SCHUNK; ++i) prod[r][i] = 1.0f;

    // H base for this wave's s-chunk: q-row = 48 float4; wave offset 12*wave
    const float4* __restrict__ Hbase = (const float4*)hHs + 12 * wave;

    // window = 2 q = 6 floats/row; one-window A prefetch per row
    float2 x[RPL][3];
    #pragma unroll
    for (int r = 0; r < RPL; ++r) {
        x[r][0] = pR[r][0]; x[r][1] = pR[r][1]; x[r][2] = pR[r][2];
    }

    #pragma unroll 5
    for (int w = 0; w < N_Q / 2; ++w) {
        const int nb = (w < N_Q / 2 - 1) ? 3 * w + 3 : 0;  // clamped, always valid
        float2 nx[RPL][3];
        #pragma unroll
        for (int r = 0; r < RPL; ++r) {
            nx[r][0] = pR[r][nb]; nx[r][1] = pR[r][nb + 1]; nx[r][2] = pR[r][nb + 2];
        }
        const float4* Hq = Hbase + 96 * w;      // q = 2w -> row offset 2w*48
        float aq[RPL][3], cq[RPL][3];
        #pragma unroll
        for (int r = 0; r < RPL; ++r) {
            aq[r][0] = x[r][0].x; aq[r][1] = x[r][0].y; aq[r][2] = x[r][1].x;
            cq[r][0] = x[r][1].y; cq[r][1] = x[r][2].x; cq[r][2] = x[r][2].y;
        }
        computeQ4(Hq,      aq, prod);           // q = 2w
        computeQ4(Hq + 48, cq, prod);           // q = 2w+1
        #pragma unroll
        for (int r = 0; r < RPL; ++r) {
            x[r][0] = nx[r][0]; x[r][1] = nx[r][1]; x[r][2] = nx[r][2];
        }
    }

    // ratio-weighted partial per row (16-long fmaf chain, same association)
    const int s0 = wave * SCHUNK;
    #pragma unroll
    for (int r = 0; r < RPL; ++r) {
        float acc = 0.0f;
        #pragma unroll
        for (int i = 0; i < SCHUNK; ++i) acc = fmaf(hrvl[s0 + i], prod[r][i], acc);
        covs[wave][64 * r + lane] = acc;
    }
    __syncthreads();

    // wave w finalizes rows [64w, 64w+64); cov = ((c0+c1)+c2)+c3 sequential
    {
        const int row = 64 * wave + lane;
        const int n = nbase + row;
        float cov = covs[0][row] + covs[1][row] + covs[2][row] + covs[3][row];
        float term = 0.0f;
        if (n < N) { float c = coeff[n]; term = (c * c) / cov; }
        double td = (double)term;
        #pragma unroll
        for (int off = 32; off; off >>= 1) td += __shfl_down(td, off);
        if (lane == 0) redd[wave] = td;
    }
    __syncthreads();

    if (tid == 0) {
        partials[blockIdx.x] = ((redd[0] + redd[1]) + redd[2]) + redd[3];
        __threadfence();                 // release partial
        int v = atomicAdd(cnt, 1);
        isLast = (v == (int)gridDim.x - 1);
    }
    __syncthreads();

    if (isLast) {                        // last-finishing block reduces all
        __threadfence();                 // acquire
        double s = 0.0;
        for (int i = tid; i < (int)gridDim.x; i += THREADS) s += partials[i];
        #pragma unroll
        for (int off = 32; off; off >>= 1) s += __shfl_down(s, off);
        if (lane == 0) redf[wave] = s;
        __syncthreads();
        if (tid == 0) {
            double t = 0.0;
            #pragma unroll
            for (int wv = 0; wv < WAVES; ++wv) t += redf[wv];
            out[0] = (float)t;
        }
    }
}

extern "C" void kernel_launch(void* const* d_in, const int* in_sizes, int n_in,
                              void* d_out, int out_size, void* d_ws, size_t ws_size,
                              hipStream_t stream) {
    const float* A           = (const float*)d_in[0];  // [N, Q, P]
    const float* coeff       = (const float*)d_in[1];  // [N]
    const float* heads_param = (const float*)d_in[2];  // [S, Q, P]
    const float* hr_param    = (const float*)d_in[3];  // [S]
    const int N = in_sizes[1];
    const int nblocks = (N + BLK_ROWS - 1) / BLK_ROWS;  // 391

    char* ws = (char*)d_ws;
    double* partials = (double*)ws;
    int*   cnt = (int*)(ws + WS_CNT_OFF);
    float* HP  = (float*)(ws + WS_HP_OFF);
    float* hrv = (float*)(ws + WS_HRV_OFF);
    float* out = (float*)d_out;

    const int pre_blocks = (N_S * N_Q + THREADS - 1) / THREADS;  // 13
    precompute_kernel<<<pre_blocks, THREADS, 0, stream>>>(heads_param, hr_param,
                                                          HP, hrv, cnt);
    main_kernel<<<nblocks, THREADS, 0, stream>>>(A, coeff, HP, hrv, partials,
                                                 cnt, out, N);
}